// Round 4
// baseline (814.287 us; speedup 1.0000x reference)
//
#include <hip/hip_runtime.h>
#include <hip/hip_bf16.h>
#include <math.h>

#define N_NODES 400000
#define N_EDGES 2400000
#define NPG 40
#define N_GRAPHS 10000
#define IN_F 30
#define H1 30
#define H2 10
#define OUTF 4
#define SCAN_NB 10      // ceil(10000/1024)
#define EDGE_CAP 1024   // LDS staging capacity for a graph's edge list

// ---------------- K1: integer degrees (int4-vectorized index reads) ----------------
__global__ void degree_kernel(const int4* __restrict__ src4, const int4* __restrict__ dst4,
                              int* __restrict__ deg_out, int* __restrict__ deg_in) {
    int i = blockIdx.x * blockDim.x + threadIdx.x;
    int stride = gridDim.x * blockDim.x;
    const int n4 = N_EDGES / 4;
    for (; i < n4; i += stride) {
        int4 s = src4[i];
        int4 d = dst4[i];
        atomicAdd(&deg_out[s.x], 1); atomicAdd(&deg_out[s.y], 1);
        atomicAdd(&deg_out[s.z], 1); atomicAdd(&deg_out[s.w], 1);
        atomicAdd(&deg_in[d.x], 1);  atomicAdd(&deg_in[d.y], 1);
        atomicAdd(&deg_in[d.z], 1);  atomicAdd(&deg_in[d.w], 1);
    }
}

// ---------------- K2: per-graph edge counts ----------------
__global__ void gsum_kernel(const int* __restrict__ deg_in, int* __restrict__ gsum) {
    int g = blockIdx.x * blockDim.x + threadIdx.x;
    if (g >= N_GRAPHS) return;
    int s = 0;
    #pragma unroll 8
    for (int k = 0; k < NPG; k++) s += deg_in[g * NPG + k];
    gsum[g] = s;
}

// ---------------- exclusive scan of gsum -> bin_start, gcursor ----------------
__global__ void scan1(const int* __restrict__ v_in, int* __restrict__ ex_out,
                      int* __restrict__ blk_sums, int n) {
    __shared__ int s[256];
    int t = threadIdx.x;
    int base = blockIdx.x * 1024 + t * 4;
    int v[4];
    #pragma unroll
    for (int k = 0; k < 4; k++) v[k] = (base + k < n) ? v_in[base + k] : 0;
    int tsum = v[0] + v[1] + v[2] + v[3];
    s[t] = tsum;
    __syncthreads();
    for (int o = 1; o < 256; o <<= 1) {
        int y = (t >= o) ? s[t - o] : 0;
        __syncthreads();
        s[t] += y;
        __syncthreads();
    }
    int run = s[t] - tsum;
    #pragma unroll
    for (int k = 0; k < 4; k++) {
        if (base + k < n) ex_out[base + k] = run;
        run += v[k];
    }
    if (t == 255) blk_sums[blockIdx.x] = s[255];
}

__global__ void scan2(const int* __restrict__ blk_sums, int* __restrict__ blk_off, int nb) {
    if (threadIdx.x == 0) {
        int run = 0;
        for (int i = 0; i < nb; i++) { blk_off[i] = run; run += blk_sums[i]; }
    }
}

__global__ void scan3(int* __restrict__ bin_start, int* __restrict__ gcursor,
                      const int* __restrict__ blk_off, int n) {
    int t = threadIdx.x;
    int off = blk_off[blockIdx.x];
    int base = blockIdx.x * 1024 + t * 4;
    #pragma unroll
    for (int k = 0; k < 4; k++) {
        int i = base + k;
        if (i < n) {
            int r = bin_start[i] + off;
            bin_start[i] = r;
            gcursor[i] = r;
        }
    }
}

// ---------------- K3: bin edges by dst graph, packed (src<<6)|dst_local ----------------
__global__ void bin_fill(const int4* __restrict__ src4, const int4* __restrict__ dst4,
                         int* __restrict__ gcursor, unsigned* __restrict__ binned) {
    int i = blockIdx.x * blockDim.x + threadIdx.x;
    int stride = gridDim.x * blockDim.x;
    const int n4 = N_EDGES / 4;
    for (; i < n4; i += stride) {
        int4 s = src4[i];
        int4 d = dst4[i];
        #pragma unroll
        for (int k = 0; k < 4; k++) {
            int dd = (k == 0) ? d.x : (k == 1) ? d.y : (k == 2) ? d.z : d.w;
            int ss = (k == 0) ? s.x : (k == 1) ? s.y : (k == 2) ? s.z : s.w;
            int g = dd / NPG;
            int dl = dd - g * NPG;
            int pos = atomicAdd(&gcursor[g], 1);
            binned[pos] = ((unsigned)ss << 6) | (unsigned)dl;
        }
    }
}

// ---------------- K4: fnorm[n][f] = bf16(feat[n][f] * rsqrt(max(deg_out,1))) padded to 32 ----
__global__ void fnorm_kernel(const float* __restrict__ feat, const int* __restrict__ deg_out,
                             ushort* __restrict__ fnorm) {
    int idx = blockIdx.x * blockDim.x + threadIdx.x;
    int n = idx >> 5;
    int f = idx & 31;
    if (n >= N_NODES) return;
    float ns = rsqrtf(fmaxf((float)deg_out[n], 1.0f));
    float v = (f < IN_F) ? feat[(size_t)n * IN_F + f] * ns : 0.f;
    __hip_bfloat16 bv = __float2bfloat16(v);
    fnorm[((size_t)n << 5) + f] = *reinterpret_cast<ushort*>(&bv);
}

// ---------------- K5: fused gather-aggregate -> @W*nd+b -> max-pool -> MLP -> sigmoid ----
__global__ __launch_bounds__(256) void agg_pool_mlp(
    const ushort* __restrict__ fnorm,
    const int* __restrict__ deg_in, const int* __restrict__ bin_start,
    const int* __restrict__ gsum, const unsigned* __restrict__ binned,
    const float* __restrict__ W, const float* __restrict__ b,
    const float* __restrict__ W2, const float* __restrict__ b2,
    const float* __restrict__ W3, const float* __restrict__ b3,
    float* __restrict__ out) {
    int g = blockIdx.x;
    int t = threadIdx.x;     // 256
    int f = t & 31;          // feature lane
    int hw = t >> 5;         // half-wave 0..7
    __shared__ float acc[NPG][33];     // stride 33: half-waves at different dl spread banks
    __shared__ float sW[IN_F * H1];
    __shared__ unsigned sE[EDGE_CAP];
    __shared__ float smax[8][32];
    __shared__ float z[H2];

    int beg = bin_start[g];
    int cnt = gsum[g];

    for (int i = t; i < NPG * 33; i += 256) ((float*)acc)[i] = 0.f;
    for (int i = t; i < IN_F * H1; i += 256) sW[i] = W[i];
    int scnt = (cnt < EDGE_CAP) ? cnt : EDGE_CAP;
    for (int i = t; i < scnt; i += 256) sE[i] = binned[beg + i];
    __syncthreads();

    // contiguous chunk per half-wave, 4x unrolled -> 4 independent gathers in flight
    int chunk = (cnt + 7) >> 3;
    int e0 = hw * chunk;
    int e1 = e0 + chunk; if (e1 > cnt) e1 = cnt;
    int e = e0;
    #define EDGEID(ee) ((ee) < EDGE_CAP ? sE[ee] : binned[beg + (ee)])
    for (; e + 4 <= e1; e += 4) {
        unsigned p0 = EDGEID(e), p1 = EDGEID(e + 1), p2 = EDGEID(e + 2), p3 = EDGEID(e + 3);
        float v0 = __bfloat162float(*reinterpret_cast<const __hip_bfloat16*>(
                       &fnorm[((size_t)(p0 >> 6) << 5) + f]));
        float v1 = __bfloat162float(*reinterpret_cast<const __hip_bfloat16*>(
                       &fnorm[((size_t)(p1 >> 6) << 5) + f]));
        float v2 = __bfloat162float(*reinterpret_cast<const __hip_bfloat16*>(
                       &fnorm[((size_t)(p2 >> 6) << 5) + f]));
        float v3 = __bfloat162float(*reinterpret_cast<const __hip_bfloat16*>(
                       &fnorm[((size_t)(p3 >> 6) << 5) + f]));
        atomicAdd(&acc[p0 & 63u][f], v0);
        atomicAdd(&acc[p1 & 63u][f], v1);
        atomicAdd(&acc[p2 & 63u][f], v2);
        atomicAdd(&acc[p3 & 63u][f], v3);
    }
    for (; e < e1; e++) {
        unsigned p = EDGEID(e);
        float v = __bfloat162float(*reinterpret_cast<const __hip_bfloat16*>(
                      &fnorm[((size_t)(p >> 6) << 5) + f]));
        atomicAdd(&acc[p & 63u][f], v);
    }
    #undef EDGEID
    __syncthreads();

    float m = -INFINITY;
    for (int n = hw; n < NPG; n += 8) {
        float nd = rsqrtf(fmaxf((float)deg_in[g * NPG + n], 1.0f));
        if (f < H1) {
            float s = 0.f;
            #pragma unroll
            for (int k = 0; k < IN_F; k++) s += acc[n][k] * sW[k * H1 + f];
            m = fmaxf(m, s * nd + b[f]);
        }
    }
    smax[hw][f] = m;
    __syncthreads();
    if (t < 32) {
        float mm = smax[0][t];
        #pragma unroll
        for (int k = 1; k < 8; k++) mm = fmaxf(mm, smax[k][t]);
        smax[0][t] = mm;   // pooled[f], valid for f < 30
    }
    __syncthreads();
    if (t < H2) {
        float s2 = b2[t];
        #pragma unroll
        for (int k = 0; k < H1; k++) s2 += smax[0][k] * W2[k * H2 + t];
        z[t] = fmaxf(s2, 0.f);
    }
    __syncthreads();
    if (t < OUTF) {
        float s3 = b3[t];
        #pragma unroll
        for (int k = 0; k < H2; k++) s3 += z[k] * W3[k * OUTF + t];
        out[g * OUTF + t] = 1.f / (1.f + expf(-s3));
    }
}

extern "C" void kernel_launch(void* const* d_in, const int* in_sizes, int n_in,
                              void* d_out, int out_size, void* d_ws, size_t ws_size,
                              hipStream_t stream) {
    const float* feat = (const float*)d_in[0];
    const int*   src  = (const int*)d_in[1];
    const int*   dst  = (const int*)d_in[2];
    const float* W  = (const float*)d_in[5];
    const float* b  = (const float*)d_in[6];
    const float* W2 = (const float*)d_in[7];
    const float* b2 = (const float*)d_in[8];
    const float* W3 = (const float*)d_in[9];
    const float* b3 = (const float*)d_in[10];
    float* out = (float*)d_out;

    char* ws = (char*)d_ws;
    int* deg_out   = (int*)ws;                     // 400000
    int* deg_in    = deg_out + N_NODES;            // 400000
    int* gsum      = deg_in + N_NODES;             // 10240 (padded)
    int* bin_start = gsum + 10240;                 // 10240
    int* gcursor   = bin_start + 10240;            // 10240
    int* blk_sums  = gcursor + 10240;              // 64
    int* blk_off   = blk_sums + 64;                // 64
    unsigned* binned = (unsigned*)(blk_off + 64);  // 2400000
    ushort* fnorm  = (ushort*)(binned + N_EDGES);  // 400000*32 bf16 = 25.6 MB

    hipMemsetAsync(deg_out, 0, sizeof(int) * 2 * N_NODES, stream);

    degree_kernel<<<2048, 256, 0, stream>>>((const int4*)src, (const int4*)dst,
                                            deg_out, deg_in);

    gsum_kernel<<<(N_GRAPHS + 255) / 256, 256, 0, stream>>>(deg_in, gsum);

    scan1<<<SCAN_NB, 256, 0, stream>>>(gsum, bin_start, blk_sums, N_GRAPHS);
    scan2<<<1, 64, 0, stream>>>(blk_sums, blk_off, SCAN_NB);
    scan3<<<SCAN_NB, 256, 0, stream>>>(bin_start, gcursor, blk_off, N_GRAPHS);

    bin_fill<<<2048, 256, 0, stream>>>((const int4*)src, (const int4*)dst,
                                       gcursor, binned);

    fnorm_kernel<<<(N_NODES * 32 + 255) / 256, 256, 0, stream>>>(feat, deg_out, fnorm);

    agg_pool_mlp<<<N_GRAPHS, 256, 0, stream>>>(fnorm, deg_in, bin_start, gsum,
                                               binned, W, b, W2, b2, W3, b3, out);
}

// Round 5
// 811.968 us; speedup vs baseline: 1.0029x; 1.0029x over previous
//
#include <hip/hip_runtime.h>
#include <hip/hip_bf16.h>
#include <math.h>

#define N_NODES 400000
#define N_EDGES 2400000
#define NPG 40
#define N_GRAPHS 10000
#define IN_F 30
#define H1 30
#define H2 10
#define OUTF 4
#define SCAN_NB 10      // ceil(10000/1024)
#define EDGE_CAP 1024   // LDS staging capacity for a graph's edge list

// ---------------- K1: integer degrees (int4-vectorized index reads) ----------------
__global__ void degree_kernel(const int4* __restrict__ src4, const int4* __restrict__ dst4,
                              int* __restrict__ deg_out, int* __restrict__ deg_in) {
    int i = blockIdx.x * blockDim.x + threadIdx.x;
    int stride = gridDim.x * blockDim.x;
    const int n4 = N_EDGES / 4;
    for (; i < n4; i += stride) {
        int4 s = src4[i];
        int4 d = dst4[i];
        atomicAdd(&deg_out[s.x], 1); atomicAdd(&deg_out[s.y], 1);
        atomicAdd(&deg_out[s.z], 1); atomicAdd(&deg_out[s.w], 1);
        atomicAdd(&deg_in[d.x], 1);  atomicAdd(&deg_in[d.y], 1);
        atomicAdd(&deg_in[d.z], 1);  atomicAdd(&deg_in[d.w], 1);
    }
}

// ---------------- K2: per-graph edge counts ----------------
__global__ void gsum_kernel(const int* __restrict__ deg_in, int* __restrict__ gsum) {
    int g = blockIdx.x * blockDim.x + threadIdx.x;
    if (g >= N_GRAPHS) return;
    int s = 0;
    #pragma unroll 8
    for (int k = 0; k < NPG; k++) s += deg_in[g * NPG + k];
    gsum[g] = s;
}

// ---------------- exclusive scan of gsum -> bin_start, gcursor ----------------
__global__ void scan1(const int* __restrict__ v_in, int* __restrict__ ex_out,
                      int* __restrict__ blk_sums, int n) {
    __shared__ int s[256];
    int t = threadIdx.x;
    int base = blockIdx.x * 1024 + t * 4;
    int v[4];
    #pragma unroll
    for (int k = 0; k < 4; k++) v[k] = (base + k < n) ? v_in[base + k] : 0;
    int tsum = v[0] + v[1] + v[2] + v[3];
    s[t] = tsum;
    __syncthreads();
    for (int o = 1; o < 256; o <<= 1) {
        int y = (t >= o) ? s[t - o] : 0;
        __syncthreads();
        s[t] += y;
        __syncthreads();
    }
    int run = s[t] - tsum;
    #pragma unroll
    for (int k = 0; k < 4; k++) {
        if (base + k < n) ex_out[base + k] = run;
        run += v[k];
    }
    if (t == 255) blk_sums[blockIdx.x] = s[255];
}

__global__ void scan2(const int* __restrict__ blk_sums, int* __restrict__ blk_off, int nb) {
    if (threadIdx.x == 0) {
        int run = 0;
        for (int i = 0; i < nb; i++) { blk_off[i] = run; run += blk_sums[i]; }
    }
}

__global__ void scan3(int* __restrict__ bin_start, int* __restrict__ gcursor,
                      const int* __restrict__ blk_off, int n) {
    int t = threadIdx.x;
    int off = blk_off[blockIdx.x];
    int base = blockIdx.x * 1024 + t * 4;
    #pragma unroll
    for (int k = 0; k < 4; k++) {
        int i = base + k;
        if (i < n) {
            int r = bin_start[i] + off;
            bin_start[i] = r;
            gcursor[i] = r;
        }
    }
}

// ---------------- K3: bin edges by dst graph, packed (src<<6)|dst_local ----------------
__global__ void bin_fill(const int4* __restrict__ src4, const int4* __restrict__ dst4,
                         int* __restrict__ gcursor, unsigned* __restrict__ binned) {
    int i = blockIdx.x * blockDim.x + threadIdx.x;
    int stride = gridDim.x * blockDim.x;
    const int n4 = N_EDGES / 4;
    for (; i < n4; i += stride) {
        int4 s = src4[i];
        int4 d = dst4[i];
        #pragma unroll
        for (int k = 0; k < 4; k++) {
            int dd = (k == 0) ? d.x : (k == 1) ? d.y : (k == 2) ? d.z : d.w;
            int ss = (k == 0) ? s.x : (k == 1) ? s.y : (k == 2) ? s.z : s.w;
            int g = dd / NPG;
            int dl = dd - g * NPG;
            int pos = atomicAdd(&gcursor[g], 1);
            binned[pos] = ((unsigned)ss << 6) | (unsigned)dl;
        }
    }
}

// ---------------- K4: fnorm[n][f] = bf16(feat[n][f] * rsqrt(max(deg_out,1))), 32-padded ----
__global__ void fnorm_kernel(const float* __restrict__ feat, const int* __restrict__ deg_out,
                             ushort* __restrict__ fnorm) {
    int idx = blockIdx.x * blockDim.x + threadIdx.x;
    int n = idx >> 5;
    int f = idx & 31;
    if (n >= N_NODES) return;
    float ns = rsqrtf(fmaxf((float)deg_out[n], 1.0f));
    float v = (f < IN_F) ? feat[(size_t)n * IN_F + f] * ns : 0.f;
    __hip_bfloat16 bv = __float2bfloat16(v);
    fnorm[((size_t)n << 5) + f] = *reinterpret_cast<ushort*>(&bv);
}

// ---------------- K5: fused gather-aggregate -> @W*nd+b -> max-pool -> MLP -> sigmoid ----
// Gather: 4 lanes per edge, uint4 (16B = 8 bf16) per lane -> 1 wave64 load = 16 edges.
__global__ __launch_bounds__(256) void agg_pool_mlp(
    const uint4* __restrict__ fnorm4,
    const int* __restrict__ deg_in, const int* __restrict__ bin_start,
    const int* __restrict__ gsum, const unsigned* __restrict__ binned,
    const float* __restrict__ W, const float* __restrict__ b,
    const float* __restrict__ W2, const float* __restrict__ b2,
    const float* __restrict__ W3, const float* __restrict__ b3,
    float* __restrict__ out) {
    int g = blockIdx.x;
    int t = threadIdx.x;     // 256
    int l = t & 3;           // lane-in-quad: which 8-feature slice of the row
    int q = t >> 2;          // quad id 0..63: which edge within a 64-edge slab
    __shared__ float acc[NPG][33];   // 33 stride: bank = (dl + 8l + j) % 32, spreads rows
    __shared__ float sW[IN_F * H1];
    __shared__ unsigned sE[EDGE_CAP];
    __shared__ float smax[8][32];
    __shared__ float z[H2];

    int beg = bin_start[g];
    int cnt = gsum[g];

    for (int i = t; i < NPG * 33; i += 256) ((float*)acc)[i] = 0.f;
    for (int i = t; i < IN_F * H1; i += 256) sW[i] = W[i];
    int scnt = (cnt < EDGE_CAP) ? cnt : EDGE_CAP;
    for (int i = t; i < scnt; i += 256) sE[i] = binned[beg + i];
    __syncthreads();

    if (cnt <= EDGE_CAP) {
        int e = q;
        // paired iterations: 2 independent gathers in flight per wave
        for (; e + 64 < cnt; e += 128) {
            unsigned p0 = sE[e];
            unsigned p1 = sE[e + 64];
            uint4 r0 = fnorm4[(size_t)(p0 >> 6) * 4 + l];
            uint4 r1 = fnorm4[(size_t)(p1 >> 6) * 4 + l];
            float* a0 = &acc[p0 & 63u][l * 8];
            float* a1 = &acc[p1 & 63u][l * 8];
            const unsigned* w0 = reinterpret_cast<const unsigned*>(&r0);
            const unsigned* w1 = reinterpret_cast<const unsigned*>(&r1);
            #pragma unroll
            for (int j = 0; j < 8; j++) {
                unsigned u = ((w0[j >> 1] >> ((j & 1) * 16)) & 0xffffu) << 16;
                atomicAdd(&a0[j], __uint_as_float(u));
            }
            #pragma unroll
            for (int j = 0; j < 8; j++) {
                unsigned u = ((w1[j >> 1] >> ((j & 1) * 16)) & 0xffffu) << 16;
                atomicAdd(&a1[j], __uint_as_float(u));
            }
        }
        if (e < cnt) {
            unsigned p = sE[e];
            uint4 r = fnorm4[(size_t)(p >> 6) * 4 + l];
            float* a = &acc[p & 63u][l * 8];
            const unsigned* w = reinterpret_cast<const unsigned*>(&r);
            #pragma unroll
            for (int j = 0; j < 8; j++) {
                unsigned u = ((w[j >> 1] >> ((j & 1) * 16)) & 0xffffu) << 16;
                atomicAdd(&a[j], __uint_as_float(u));
            }
        }
    } else {
        // overflow fallback (statistically never at avg deg 240): read ids from global
        for (int e = q; e < cnt; e += 64) {
            unsigned p = binned[beg + e];
            uint4 r = fnorm4[(size_t)(p >> 6) * 4 + l];
            float* a = &acc[p & 63u][l * 8];
            const unsigned* w = reinterpret_cast<const unsigned*>(&r);
            #pragma unroll
            for (int j = 0; j < 8; j++) {
                unsigned u = ((w[j >> 1] >> ((j & 1) * 16)) & 0xffffu) << 16;
                atomicAdd(&a[j], __uint_as_float(u));
            }
        }
    }
    __syncthreads();

    int f = t & 31;
    int hw = t >> 5;
    float m = -INFINITY;
    for (int n = hw; n < NPG; n += 8) {
        float nd = rsqrtf(fmaxf((float)deg_in[g * NPG + n], 1.0f));
        if (f < H1) {
            float s = 0.f;
            #pragma unroll
            for (int k = 0; k < IN_F; k++) s += acc[n][k] * sW[k * H1 + f];
            m = fmaxf(m, s * nd + b[f]);
        }
    }
    smax[hw][f] = m;
    __syncthreads();
    if (t < 32) {
        float mm = smax[0][t];
        #pragma unroll
        for (int k = 1; k < 8; k++) mm = fmaxf(mm, smax[k][t]);
        smax[0][t] = mm;   // pooled[f], valid for f < 30
    }
    __syncthreads();
    if (t < H2) {
        float s2 = b2[t];
        #pragma unroll
        for (int k = 0; k < H1; k++) s2 += smax[0][k] * W2[k * H2 + t];
        z[t] = fmaxf(s2, 0.f);
    }
    __syncthreads();
    if (t < OUTF) {
        float s3 = b3[t];
        #pragma unroll
        for (int k = 0; k < H2; k++) s3 += z[k] * W3[k * OUTF + t];
        out[g * OUTF + t] = 1.f / (1.f + expf(-s3));
    }
}

extern "C" void kernel_launch(void* const* d_in, const int* in_sizes, int n_in,
                              void* d_out, int out_size, void* d_ws, size_t ws_size,
                              hipStream_t stream) {
    const float* feat = (const float*)d_in[0];
    const int*   src  = (const int*)d_in[1];
    const int*   dst  = (const int*)d_in[2];
    const float* W  = (const float*)d_in[5];
    const float* b  = (const float*)d_in[6];
    const float* W2 = (const float*)d_in[7];
    const float* b2 = (const float*)d_in[8];
    const float* W3 = (const float*)d_in[9];
    const float* b3 = (const float*)d_in[10];
    float* out = (float*)d_out;

    char* ws = (char*)d_ws;
    int* deg_out   = (int*)ws;                     // 400000
    int* deg_in    = deg_out + N_NODES;            // 400000
    int* gsum      = deg_in + N_NODES;             // 10240 (padded)
    int* bin_start = gsum + 10240;                 // 10240
    int* gcursor   = bin_start + 10240;            // 10240
    int* blk_sums  = gcursor + 10240;              // 64
    int* blk_off   = blk_sums + 64;                // 64
    unsigned* binned = (unsigned*)(blk_off + 64);  // 2400000 (offset 64B-aligned)
    ushort* fnorm  = (ushort*)(binned + N_EDGES);  // 400000*32 bf16 = 25.6 MB, 64B-aligned

    hipMemsetAsync(deg_out, 0, sizeof(int) * 2 * N_NODES, stream);

    degree_kernel<<<2048, 256, 0, stream>>>((const int4*)src, (const int4*)dst,
                                            deg_out, deg_in);

    gsum_kernel<<<(N_GRAPHS + 255) / 256, 256, 0, stream>>>(deg_in, gsum);

    scan1<<<SCAN_NB, 256, 0, stream>>>(gsum, bin_start, blk_sums, N_GRAPHS);
    scan2<<<1, 64, 0, stream>>>(blk_sums, blk_off, SCAN_NB);
    scan3<<<SCAN_NB, 256, 0, stream>>>(bin_start, gcursor, blk_off, N_GRAPHS);

    bin_fill<<<2048, 256, 0, stream>>>((const int4*)src, (const int4*)dst,
                                       gcursor, binned);

    fnorm_kernel<<<(N_NODES * 32 + 255) / 256, 256, 0, stream>>>(feat, deg_out, fnorm);

    agg_pool_mlp<<<N_GRAPHS, 256, 0, stream>>>((const uint4*)fnorm, deg_in, bin_start,
                                               gsum, binned, W, b, W2, b2, W3, b3, out);
}